// Round 15
// baseline (153.147 us; speedup 1.0000x reference)
//
#include <hip/hip_runtime.h>
#include <math.h>

#define NN 512
#define SD 32
#define HM 64

typedef _Float16 f16x8 __attribute__((ext_vector_type(8)));
typedef float floatx4 __attribute__((ext_vector_type(4)));
typedef unsigned uintx4 __attribute__((ext_vector_type(4)));

// ---- step-kernel dynamic LDS layout (bytes) ----
#define OFF_HBS   0        // 512 rows x 144 B packed-f16 hip        = 73728
#define OFF_M2L   73728    // 8 waves x 2304 B                       = 18432
#define OFF_MSUM  92160    // 8x32 f32
#define OFF_HPREV 93184    // 2x32 f32
#define OFF_HS    93440    // 2x32 f32
#define OFF_MSG   93696    // 2x32 f32
#define OFF_GI    93952    // 2x96 f32
#define OFF_GH    94720    // 2x96 f32
#define OFF_HJPS  95488    // 2x64 f32 (step-0 local hjp)
#define OFF_W65   96000    // 64 f32 (step-0 W1 col 65)
#define LDS_TOTAL 96256

__device__ __forceinline__ float sigmoidf_(float x) {
    return 1.0f / (1.0f + __expf(-x));
}
__device__ __forceinline__ unsigned pkrtz(float a, float b) {
    unsigned r;
    asm("v_cvt_pkrtz_f16_f32 %0, %1, %2" : "=v"(r) : "v"(a), "v"(b));
    return r;
}
__device__ __forceinline__ unsigned pk_add(unsigned a, unsigned b) {
    unsigned r;
    asm("v_pk_add_f16 %0, %1, %2" : "=v"(r) : "v"(a), "v"(b));
    return r;
}
__device__ __forceinline__ unsigned pk_fma(unsigned a, unsigned b, unsigned c) {
    unsigned r;
    asm("v_pk_fma_f16 %0, %1, %2, %3" : "=v"(r) : "v"(a), "v"(b), "v"(c));
    return r;
}
__device__ __forceinline__ unsigned pk_relu(unsigned a) {
    unsigned r, z = 0u;
    asm("v_pk_max_f16 %0, %1, %2" : "=v"(r) : "v"(a), "v"(z));
    return r;
}

// ---------------------------------------------------------------------------
struct SParams {
    const unsigned *hbR;  unsigned *hbW;
    const unsigned *hjR;  unsigned *hjW;
    const float *hR;      float *hW;
    // shared precomputes (written during step 0, read in steps 1-4)
    float *JT, *W1T, *WihT, *WhhT, *rW1T, *rW2T;
    unsigned *w2p, *w3p, *wjp;
    // raw inputs
    const float *J, *mpW1, *mpb1, *mpW2, *mpb2, *mpW3, *mpb3;
    const float *Wih, *Whh, *bih, *bhh, *b;
    const float *rW1, *rW2, *rW3, *rb1, *rb2, *rb3;
    float *out;
    int hzero, rdout;
};

// One message-passing step; 256 blocks x 512 threads, block owns nodes
// 2*bid, 2*bid+1. Step 0 (hzero): hip0 = b*W1[:,65] is rank-1 -> each block
// synthesizes the full hb LDS tile locally (no exchange), reads J strided,
// writes JT + transposes/prepacks for steps 1-4. Steps 1-4: coalesced
// JT/prepack reads, hb from global (written by step t-1). Cross-dispatch
// coherence via stream ordering — no barriers, no cache-bypass.
__global__ __launch_bounds__(512, 1) void step_kernel(SParams s)
{
    extern __shared__ __align__(16) char smem[];
    char* hbS = smem + OFF_HBS;
    float (*msum)[32]   = (float(*)[32])(smem + OFF_MSUM);
    float (*hPrevS)[32] = (float(*)[32])(smem + OFF_HPREV);
    float (*hS)[32]     = (float(*)[32])(smem + OFF_HS);
    float (*msgS)[32]   = (float(*)[32])(smem + OFF_MSG);
    float (*giS)[96]    = (float(*)[96])(smem + OFF_GI);
    float (*ghS)[96]    = (float(*)[96])(smem + OFF_GH);
    float (*hjpS)[64]   = (float(*)[64])(smem + OFF_HJPS);
    float* w65S         = (float*)(smem + OFF_W65);

    const int tid  = threadIdx.x;
    const int lane = tid & 63;
    const int wave = tid >> 6;
    const int nsel = wave >> 2;
    const int nw   = wave & 3;
    const int j    = blockIdx.x * 2 + nsel;
    const int q    = lane >> 4;
    const int c    = lane & 15;
    char* m2Lw = smem + OFF_M2L + wave * 2304;

    if (s.hzero) {
        // ---- shared precompute duties (visible at next dispatch) ----
        if (blockIdx.x == 1) {
            for (int n = tid; n < 64 * 67; n += 512) {
                int cc = n / 67, d = n % 67;
                s.W1T[d * 64 + cc] = s.mpW1[n];
            }
        } else if (blockIdx.x == 2) {
            for (int n = tid; n < 96 * 64; n += 512)
                s.WihT[(n & 63) * 96 + (n >> 6)] = s.Wih[n];
        } else if (blockIdx.x == 3) {
            for (int n = tid; n < 96 * 32; n += 512)
                s.WhhT[(n & 31) * 96 + (n >> 5)] = s.Whh[n];
        } else if (blockIdx.x == 4) {
            for (int n = tid; n < 64 * 32; n += 512)
                s.rW1T[(n & 31) * 64 + (n >> 5)] = s.rW1[n];
            for (int n = tid; n < 64 * 64; n += 512)
                s.rW2T[(n & 63) * 64 + (n >> 6)] = s.rW2[n];
        } else if (blockIdx.x == 5 && tid < 64) {
            int l = tid, qq = l >> 4, cc = l & 15;
            for (int f = 0; f < 2; ++f)
                for (int t4 = 0; t4 < 4; ++t4) {
                    const float* src = s.mpW2 + (t4 * 16 + cc) * 64 + f * 32 + qq * 8;
                    unsigned* dst = s.w2p + ((f * 4 + t4) * 64 + l) * 4;
                    for (int i = 0; i < 4; ++i) dst[i] = pkrtz(src[2 * i], src[2 * i + 1]);
                }
            for (int f = 0; f < 2; ++f)
                for (int t2 = 0; t2 < 2; ++t2) {
                    const float* src = s.mpW3 + (t2 * 16 + cc) * 64 + f * 32 + qq * 8;
                    unsigned* dst = s.w3p + ((f * 2 + t2) * 64 + l) * 4;
                    for (int i = 0; i < 4; ++i) dst[i] = pkrtz(src[2 * i], src[2 * i + 1]);
                }
            for (int s2 = 0; s2 < 2; ++s2) {
                unsigned* dst = s.wjp + (s2 * 64 + l) * 4;
                for (int i = 0; i < 4; ++i) {
                    int r0 = qq * 8 + 2 * i + s2 * 32;
                    dst[i] = pkrtz(s.mpW1[r0 * 67 + 64], s.mpW1[(r0 + 1) * 67 + 64]);
                }
            }
        }
        // ---- local prep: w65, hjp ----
        if (tid < 64) w65S[tid] = s.mpW1[tid * 67 + 65];
        if (tid < 128) {
            int node = tid >> 6, cc = tid & 63;
            int jj = blockIdx.x * 2 + node;
            float bj = s.b[jj];
            hjpS[node][cc] = bj * s.mpW1[cc * 67 + 66] + s.mpb1[cc];
        }
        __syncthreads();
        // ---- synthesize hb tile locally: row t = b[t] * w65 (packed f16) ----
        {
            float bi = s.b[tid];
            unsigned* dst = (unsigned*)(hbS + tid * 144);
            #pragma unroll
            for (int k8 = 0; k8 < 8; ++k8) {
                uintx4 v;
                #pragma unroll
                for (int i = 0; i < 4; ++i) {
                    int k = k8 * 4 + i;
                    v[i] = pkrtz(bi * w65S[2 * k], bi * w65S[2 * k + 1]);
                }
                *(uintx4*)(dst + k8 * 4) = v;
            }
        }
    } else {
        // ---- stage hb (64 KB) from global -> LDS ----
        uintx4 cr[8];
        const uintx4* gp = (const uintx4*)s.hbR;
        #pragma unroll
        for (int k = 0; k < 8; ++k) cr[k] = gp[k * 512 + tid];
        #pragma unroll
        for (int k = 0; k < 8; ++k) {
            int row = k * 64 + (tid >> 3);
            *(uintx4*)(hbS + row * 144 + (tid & 7) * 16) = cr[k];
        }
        if (tid < 64)
            hPrevS[tid >> 5][tid & 31] = s.hR[blockIdx.x * 64 + tid];
    }
    __syncthreads();

    // ---- per-lane operand setup ----
    f16x8 Aw2[2][4], Aw3[2][2];
    uintx4 wja, wjb, hja, hjb;
    if (s.hzero) {
        #pragma unroll
        for (int f = 0; f < 2; ++f)
            #pragma unroll
            for (int t4 = 0; t4 < 4; ++t4) {
                const float* src = s.mpW2 + (t4 * 16 + c) * 64 + f * 32 + q * 8;
                #pragma unroll
                for (int i = 0; i < 8; ++i) Aw2[f][t4][i] = (_Float16)src[i];
            }
        #pragma unroll
        for (int f = 0; f < 2; ++f)
            #pragma unroll
            for (int t2 = 0; t2 < 2; ++t2) {
                const float* src = s.mpW3 + (t2 * 16 + c) * 64 + f * 32 + q * 8;
                #pragma unroll
                for (int i = 0; i < 8; ++i) Aw3[f][t2][i] = (_Float16)src[i];
            }
        #pragma unroll
        for (int i = 0; i < 4; ++i) {
            wja[i] = pkrtz(s.mpW1[(q * 8 + 2 * i) * 67 + 64],
                           s.mpW1[(q * 8 + 2 * i + 1) * 67 + 64]);
            wjb[i] = pkrtz(s.mpW1[(q * 8 + 2 * i + 32) * 67 + 64],
                           s.mpW1[(q * 8 + 2 * i + 33) * 67 + 64]);
            hja[i] = pkrtz(hjpS[nsel][q * 8 + 2 * i], hjpS[nsel][q * 8 + 2 * i + 1]);
            hjb[i] = pkrtz(hjpS[nsel][q * 8 + 2 * i + 32], hjpS[nsel][q * 8 + 2 * i + 33]);
        }
    } else {
        #pragma unroll
        for (int f = 0; f < 2; ++f)
            #pragma unroll
            for (int t4 = 0; t4 < 4; ++t4)
                Aw2[f][t4] = __builtin_bit_cast(f16x8,
                    ((const uintx4*)s.w2p)[(f * 4 + t4) * 64 + lane]);
        #pragma unroll
        for (int f = 0; f < 2; ++f)
            #pragma unroll
            for (int t2 = 0; t2 < 2; ++t2)
                Aw3[f][t2] = __builtin_bit_cast(f16x8,
                    ((const uintx4*)s.w3p)[(f * 2 + t2) * 64 + lane]);
        wja = ((const uintx4*)s.wjp)[lane];
        wjb = ((const uintx4*)s.wjp)[64 + lane];
        hja = ((const uintx4*)s.hjR)[j * 8 + q];
        hjb = ((const uintx4*)s.hjR)[j * 8 + 4 + q];
    }

    floatx4 b2i[4], b3i[2];
    #pragma unroll
    for (int t4 = 0; t4 < 4; ++t4)
        #pragma unroll
        for (int r = 0; r < 4; ++r) b2i[t4][r] = s.mpb2[t4 * 16 + q * 4 + r];
    #pragma unroll
    for (int t2 = 0; t2 < 2; ++t2)
        #pragma unroll
        for (int r = 0; r < 4; ++r) b3i[t2][r] = s.mpb3[t2 * 16 + q * 4 + r];

    float jA, jB;
    if (s.hzero) {
        jA = s.J[((8 * q + nw) * 16 + c) * NN + j];
        jB = s.J[((8 * q + 4 + nw) * 16 + c) * NN + j];
        s.JT[j * NN + (8 * q + nw) * 16 + c] = jA;       // for steps 1-4
        s.JT[j * NN + (8 * q + 4 + nw) * 16 + c] = jB;
    } else {
        jA = s.JT[j * NN + (8 * q + nw) * 16 + c];
        jB = s.JT[j * NN + (8 * q + 4 + nw) * 16 + c];
    }

    float accf[2][4];
    #pragma unroll
    for (int t2 = 0; t2 < 2; ++t2)
        #pragma unroll
        for (int r = 0; r < 4; ++r) accf[t2][r] = 0.0f;

    auto edge_group = [&](int G, float Jv) {
        const char* rb = hbS + (G * 16 + c) * 144;
        uintx4 vlo = *(const uintx4*)(rb + q * 16);
        uintx4 vhi = *(const uintx4*)(rb + 64 + q * 16);
        const unsigned Jp = pkrtz(Jv, Jv);

        uintx4 a0u, a1u;
        #pragma unroll
        for (int i = 0; i < 4; ++i) {
            a0u[i] = pk_relu(pk_fma(Jp, wja[i], pk_add(vlo[i], hja[i])));
            a1u[i] = pk_relu(pk_fma(Jp, wjb[i], pk_add(vhi[i], hjb[i])));
        }
        f16x8 B0 = __builtin_bit_cast(f16x8, a0u);
        f16x8 B1 = __builtin_bit_cast(f16x8, a1u);

        floatx4 c1[4];
        #pragma unroll
        for (int t4 = 0; t4 < 4; ++t4) {
            c1[t4] = __builtin_amdgcn_mfma_f32_16x16x32_f16(Aw2[0][t4], B0, b2i[t4], 0, 0, 0);
            c1[t4] = __builtin_amdgcn_mfma_f32_16x16x32_f16(Aw2[1][t4], B1, c1[t4], 0, 0, 0);
        }
        #pragma unroll
        for (int t4 = 0; t4 < 4; ++t4) {
            unsigned p0 = pkrtz(fmaxf(c1[t4][0], 0.f), fmaxf(c1[t4][1], 0.f));
            unsigned p1 = pkrtz(fmaxf(c1[t4][2], 0.f), fmaxf(c1[t4][3], 0.f));
            *(uint2*)(m2Lw + c * 144 + t4 * 32 + q * 8) = make_uint2(p0, p1);
        }
        uintx4 rlo = *(const uintx4*)(m2Lw + c * 144 + q * 16);
        uintx4 rhi = *(const uintx4*)(m2Lw + c * 144 + 64 + q * 16);
        f16x8 B2lo = __builtin_bit_cast(f16x8, rlo);
        f16x8 B2hi = __builtin_bit_cast(f16x8, rhi);

        floatx4 c2[2];
        #pragma unroll
        for (int t2 = 0; t2 < 2; ++t2) {
            c2[t2] = __builtin_amdgcn_mfma_f32_16x16x32_f16(Aw3[0][t2], B2lo, b3i[t2], 0, 0, 0);
            c2[t2] = __builtin_amdgcn_mfma_f32_16x16x32_f16(Aw3[1][t2], B2hi, c2[t2], 0, 0, 0);
        }
        #pragma unroll
        for (int t2 = 0; t2 < 2; ++t2)
            #pragma unroll
            for (int r = 0; r < 4; ++r)
                accf[t2][r] += fmaxf(c2[t2][r], 0.0f);
    };

    #pragma unroll
    for (int k = 0; k < 4; ++k) {
        edge_group(8 * k + nw,     __shfl(jA, k * 16 + c));
        edge_group(8 * k + 4 + nw, __shfl(jB, k * 16 + c));
    }

    #pragma unroll
    for (int m = 1; m < 16; m <<= 1)
        #pragma unroll
        for (int t2 = 0; t2 < 2; ++t2)
            #pragma unroll
            for (int r = 0; r < 4; ++r)
                accf[t2][r] += __shfl_xor(accf[t2][r], m);
    if (c == 0) {
        #pragma unroll
        for (int t2 = 0; t2 < 2; ++t2)
            #pragma unroll
            for (int r = 0; r < 4; ++r)
                msum[wave][t2 * 16 + q * 4 + r] = accf[t2][r];
    }
    __syncthreads();

    if (tid < 64) {
        int node = tid >> 5, d = tid & 31;
        msgS[node][d] = msum[node * 4 + 0][d] + msum[node * 4 + 1][d] +
                        msum[node * 4 + 2][d] + msum[node * 4 + 3][d];
    }
    __syncthreads();

    if (tid < 192) {
        int node = tid / 96, r = tid % 96;
        float a  = s.bih[r];
        float bb = s.bhh[r];
        if (!s.hzero) {
            #pragma unroll
            for (int k = 0; k < 32; ++k) {
                float hv = hPrevS[node][k];
                a  = fmaf(hv, s.WihT[k * 96 + r], a);
                bb = fmaf(hv, s.WhhT[k * 96 + r], bb);
            }
            #pragma unroll
            for (int k = 0; k < 32; ++k)
                a = fmaf(msgS[node][k], s.WihT[(32 + k) * 96 + r], a);
        } else {
            #pragma unroll
            for (int k = 0; k < 32; ++k)
                a = fmaf(msgS[node][k], s.Wih[r * 64 + 32 + k], a);
        }
        giS[node][r] = a; ghS[node][r] = bb;
    }
    __syncthreads();

    if (tid < 64) {
        int node = tid >> 5, d = tid & 31;
        float r  = sigmoidf_(giS[node][d] + ghS[node][d]);
        float z  = sigmoidf_(giS[node][32 + d] + ghS[node][32 + d]);
        float ng = tanhf(giS[node][64 + d] + r * ghS[node][64 + d]);
        float hold = s.hzero ? 0.0f : hPrevS[node][d];
        float hv = (1.0f - z) * ng + z * hold;
        hS[node][d] = hv;
        s.hW[blockIdx.x * 64 + tid] = hv;
    }
    __syncthreads();

    if (!s.rdout) {
        if (tid < 128) {
            int node = tid >> 6, cc = tid & 63;
            int jj = blockIdx.x * 2 + node;
            float bj = s.b[jj];
            float si, sj;
            if (s.hzero) {
                si = bj * s.mpW1[cc * 67 + 65];
                sj = bj * s.mpW1[cc * 67 + 66] + s.mpb1[cc];
                #pragma unroll
                for (int d = 0; d < 32; ++d) {
                    float hv = hS[node][d];
                    si = fmaf(hv, s.mpW1[cc * 67 + d], si);
                    sj = fmaf(hv, s.mpW1[cc * 67 + 32 + d], sj);
                }
            } else {
                si = bj * s.W1T[65 * 64 + cc];
                sj = bj * s.W1T[66 * 64 + cc] + s.mpb1[cc];
                #pragma unroll
                for (int d = 0; d < 32; ++d) {
                    float hv = hS[node][d];
                    si = fmaf(hv, s.W1T[d * 64 + cc], si);
                    sj = fmaf(hv, s.W1T[(32 + d) * 64 + cc], sj);
                }
            }
            float sip = __shfl(si, lane ^ 1);
            float sjp = __shfl(sj, lane ^ 1);
            if (!(cc & 1)) {
                s.hbW[jj * 32 + (cc >> 1)] = pkrtz(si, sip);
                s.hjW[jj * 32 + (cc >> 1)] = pkrtz(sj, sjp);
            }
        }
    } else {
        if (wave < 2) {
            int node = wave;
            int jj = blockIdx.x * 2 + node;
            float y1 = s.rb1[lane];
            #pragma unroll
            for (int k = 0; k < 32; ++k)
                y1 = fmaf(hS[node][k], s.rW1T[k * 64 + lane], y1);
            y1 = fmaxf(y1, 0.0f);
            float y2 = s.rb2[lane];
            #pragma unroll
            for (int k = 0; k < 64; ++k)
                y2 = fmaf(__shfl(y1, k), s.rW2T[k * 64 + lane], y2);
            y2 = fmaxf(y2, 0.0f);
            float y3 = (lane < 2) ? s.rb3[lane] : 0.0f;
            #pragma unroll
            for (int k = 0; k < 64; ++k) {
                float v = __shfl(y2, k);
                if (lane < 2) y3 = fmaf(v, s.rW3[lane * 64 + k], y3);
            }
            if (lane < 2) s.out[jj * 2 + lane] = sigmoidf_(y3);
        }
    }
}

// ---------------------------------------------------------------------------
extern "C" void kernel_launch(void* const* d_in, const int* in_sizes, int n_in,
                              void* d_out, int out_size, void* d_ws, size_t ws_size,
                              hipStream_t stream)
{
    float* ws = (float*)d_ws;

    SParams s;
    s.J    = (const float*)d_in[0];
    s.b    = (const float*)d_in[1];
    s.mpW1 = (const float*)d_in[2];
    s.mpb1 = (const float*)d_in[3];
    s.mpW2 = (const float*)d_in[4];
    s.mpb2 = (const float*)d_in[5];
    s.mpW3 = (const float*)d_in[6];
    s.mpb3 = (const float*)d_in[7];
    s.Wih  = (const float*)d_in[8];
    s.Whh  = (const float*)d_in[9];
    s.bih  = (const float*)d_in[10];
    s.bhh  = (const float*)d_in[11];
    s.rW1  = (const float*)d_in[12];
    s.rb1  = (const float*)d_in[13];
    s.rW2  = (const float*)d_in[14];
    s.rb2  = (const float*)d_in[15];
    s.rW3  = (const float*)d_in[16];
    s.rb3  = (const float*)d_in[17];
    s.out  = (float*)d_out;

    s.JT   = ws;                              // 262144 f32
    s.W1T  = ws + 262144;                     // 4288
    s.WihT = ws + 266432;                     // 6144
    s.WhhT = ws + 272576;                     // 3072
    s.rW1T = ws + 275648;                     // 2048
    s.rW2T = ws + 277696;                     // 4096
    s.w2p  = (unsigned*)(ws + 281792);        // 2048 u32
    s.w3p  = (unsigned*)(ws + 283840);        // 1024 u32
    s.wjp  = (unsigned*)(ws + 284864);        // 512 u32
    unsigned* hb0 = (unsigned*)(ws + 285376); // 16384 u32
    unsigned* hb1 = (unsigned*)(ws + 301760);
    unsigned* hj0 = (unsigned*)(ws + 318144);
    unsigned* hj1 = (unsigned*)(ws + 334528);
    float*    h0  = ws + 350912;
    float*    h1  = ws + 367296;

    (void)hipFuncSetAttribute((const void*)step_kernel,
                              hipFuncAttributeMaxDynamicSharedMemorySize, LDS_TOTAL);

    for (int t = 0; t < 5; ++t) {
        s.hbR = (t & 1) ? hb1 : hb0;
        s.hbW = (t & 1) ? hb0 : hb1;
        s.hjR = (t & 1) ? hj1 : hj0;
        s.hjW = (t & 1) ? hj0 : hj1;
        s.hR  = (t & 1) ? h0 : h1;
        s.hW  = (t & 1) ? h1 : h0;
        s.hzero = (t == 0);
        s.rdout = (t == 4);
        step_kernel<<<dim3(256), dim3(512), LDS_TOTAL, stream>>>(s);
    }
}